// Round 23
// baseline (158.065 us; speedup 1.0000x reference)
//
#include <hip/hip_runtime.h>
#include <math.h>

// GCNII graph convolution, N=50000, F=256, E=800000, f32 in/out.
// R23: R22 + (1) gather Af-stores coalesced via 4-row LDS staging (2KB,
//      one barrier; 128B-contiguous frag writes vs 16B granules -- R22
//      WRITE_SIZE showed 47% partial-line overhead) and (2) CHUNK=10000:
//      hist 80->160 blocks (CU coverage 31->62%), total edge reads
//      unchanged (edge-range split, NOT R12's node-range re-scan mistake).
//      gemm (zero-LDS fragment-major A+B, ~30us) unchanged.

#define F_DIM 256
#define CHUNK 10000

typedef __attribute__((ext_vector_type(4))) float f32x4;
typedef __attribute__((ext_vector_type(8))) short short8;
typedef __attribute__((ext_vector_type(4))) unsigned short u16x4;

static __device__ __forceinline__ unsigned short f2bf(float f) {
    unsigned int u = __float_as_uint(f);
    u += 0x7fffu + ((u >> 16) & 1u);
    return (unsigned short)(u >> 16);
}
static __device__ __forceinline__ float bf2f(unsigned short u) {
    return __uint_as_float((unsigned int)u << 16);
}

// ---- histogram: block = (chunk c, which). u8x4-packed LDS, all nodes ------

__global__ __launch_bounds__(1024) void hist_kernel(
        const int* __restrict__ src, const int* __restrict__ dst,
        unsigned* __restrict__ histS, unsigned* __restrict__ histD,
        unsigned char* __restrict__ lrank, int E, int wpc4) {
    __shared__ unsigned hist[12544];
    int b = blockIdx.x;
    int which = b & 1, c = b >> 1;
    int tid = threadIdx.x;
    int e0 = c * CHUNK;
    int e1 = e0 + CHUNK < E ? e0 + CHUNK : E;
    const int* eptr = which ? dst : src;
    unsigned* outh = which ? histD : histS;

    for (int w = tid; w < wpc4; w += 1024) hist[w] = 0;
    __syncthreads();
    for (int e = e0 + tid; e < e1; e += 1024) {
        int s = eptr[e];
        int sh = (s & 3) * 8;
        unsigned old = atomicAdd(&hist[s >> 2], 1u << sh);
        if (!which) lrank[e] = (unsigned char)((old >> sh) & 0xffu);
    }
    __syncthreads();
    for (int w = tid; w < wpc4; w += 1024)
        outh[(size_t)c * wpc4 + w] = hist[w];
}

// ---- histS/histD pass: cnt, dinv, u8-packed per-chunk bases, blk sums -----

__global__ __launch_bounds__(256) void sumbase_kernel(
        const unsigned* __restrict__ histS, const unsigned* __restrict__ histD,
        int* __restrict__ cnt, float* __restrict__ dinv,
        unsigned* __restrict__ baseL, int* __restrict__ blksum,
        int wpc4, int nchunk, int n) {
    int tid = threadIdx.x;
    int w = blockIdx.x * 256 + tid;
    unsigned s0 = 0, s1 = 0, s2 = 0, s3 = 0;
    unsigned d0 = 0, d1 = 0, d2 = 0, d3 = 0;
    if (w < wpc4) {
        for (int c = 0; c < nchunk; ++c) {
            unsigned vs = histS[(size_t)c * wpc4 + w];
            unsigned vd = histD[(size_t)c * wpc4 + w];
            baseL[(size_t)c * wpc4 + w] = s0 | (s1 << 8) | (s2 << 16) | (s3 << 24);
            s0 += vs & 0xffu; s1 += (vs >> 8) & 0xffu;
            s2 += (vs >> 16) & 0xffu; s3 += vs >> 24;
            d0 += vd & 0xffu; d1 += (vd >> 8) & 0xffu;
            d2 += (vd >> 16) & 0xffu; d3 += vd >> 24;
        }
        int i0 = 4 * w;
        unsigned sv[4] = {s0, s1, s2, s3};
        unsigned dv[4] = {d0, d1, d2, d3};
        for (int k = 0; k < 4; ++k) {
            if (i0 + k < n) {
                cnt[i0 + k] = (int)sv[k];
                dinv[i0 + k] = rsqrtf((float)dv[k] + 1.0f);
            }
        }
    }
    int contrib = (w < wpc4) ? (int)(s0 + s1 + s2 + s3) : 0;
    int lane = tid & 63, wid = tid >> 6;
    int v = contrib;
    for (int off = 32; off > 0; off >>= 1) v += __shfl_down(v, off, 64);
    if (lane == 0) blksum[4 * blockIdx.x + wid] = v;
}

// ---- row_ptr: per-block self-scan of blksum + local scan ------------------

__global__ __launch_bounds__(256) void rowptr_kernel(const int* __restrict__ cnt,
                                                     const int* __restrict__ blksum,
                                                     int* __restrict__ row_ptr,
                                                     int n, int nb) {
    int tid = threadIdx.x;
    int lane = tid & 63, w = tid >> 6;
    int bv = (tid < nb) ? blksum[tid] : 0;
    int bs = bv;
    for (int off = 1; off < 64; off <<= 1) {
        int t = __shfl_up(bv, off, 64);
        if (lane >= off) bv += t;
    }
    __shared__ int wsb[4];
    __shared__ int sbo[256];
    if (lane == 63) wsb[w] = bv;
    __syncthreads();
    if (tid == 0) {
        int run = 0;
        for (int k = 0; k < 4; ++k) { int t = wsb[k]; wsb[k] = run; run += t; }
    }
    __syncthreads();
    sbo[tid] = wsb[w] + bv - bs;
    __syncthreads();
    int blockoff = sbo[blockIdx.x];
    int i = blockIdx.x * 256 + tid;
    int s = (i < n) ? cnt[i] : 0;
    int v = s;
    for (int off = 1; off < 64; off <<= 1) {
        int t = __shfl_up(v, off, 64);
        if (lane >= off) v += t;
    }
    __shared__ int ws[4];
    if (lane == 63) ws[w] = v;
    __syncthreads();
    if (tid == 0) {
        int run = 0;
        for (int k = 0; k < 4; ++k) { int t = ws[k]; ws[k] = run; run += t; }
    }
    __syncthreads();
    if (i <= n) row_ptr[i] = blockoff + ws[w] + v - s;
}

// ---- merged: fill + Hs build + Wtp build (fragment-major) -----------------

__global__ __launch_bounds__(256) void fillhswt_kernel(
        const int* __restrict__ src, const int* __restrict__ dst,
        const int* __restrict__ row_ptr, const unsigned char* __restrict__ baseL8,
        const unsigned char* __restrict__ lrank, int* __restrict__ col,
        const float* __restrict__ H, const float* __restrict__ dinv,
        unsigned short* __restrict__ Hs,
        const float* __restrict__ W, unsigned short* __restrict__ Wtp,
        const float* __restrict__ lamda_p, const int* __restrict__ l_p,
        int E, int wpc4, int nfill, int total4) {
    int bid = blockIdx.x;
    int tid = threadIdx.x;
    if (bid < nfill) {
        int e = bid * 256 + tid;
        if (e < E) {
            int c = e / CHUNK;
            int s = src[e];
            unsigned lb = baseL8[(size_t)c * (4 * wpc4) + s];
            unsigned pos = (unsigned)row_ptr[s] + lb + lrank[e];
            col[pos] = dst[e];
        }
    } else {
        int i = (bid - nfill) * 256 + tid;   // f32x4 / u16x4 units
        if (i < total4) {
            int row = i >> 6;                 // 64 x f32x4 per row
            float d = dinv[row];
            f32x4 x = ((const f32x4*)H)[i];
            u16x4 o;
            o[0] = f2bf(x[0] * d); o[1] = f2bf(x[1] * d);
            o[2] = f2bf(x[2] * d); o[3] = f2bf(x[3] * d);
            ((u16x4*)Hs)[i] = o;
        } else {
            int t = i - total4;               // 0..65535 -> Wtp build
            if (t < F_DIM * F_DIM) {
                float beta = logf(lamda_p[0] / (float)l_p[0] + 1.0f);
                int nn = t >> 8, kf = t & 255;          // col, k
                float v = beta * W[kf * F_DIM + nn];
                if (kf == nn) v += 1.0f - beta;
                int cb = nn >> 4, lo = nn & 15;
                int kk = kf >> 5, ks = kf & 31;
                int hi = ks >> 3, el = ks & 7;
                int lane = hi * 16 + lo;
                Wtp[(((size_t)cb * 8 + kk) * 64 + lane) * 8 + el] = f2bf(v);
            }
        }
    }
}

// ---- gather: wave per row, 8-deep unroll; 4-row LDS stage -> coalesced
// fragment-major Af stores (128B-contiguous chunks).

#define ACC(A, h) { A[0] += bf2f(h[0]); A[1] += bf2f(h[1]); \
                    A[2] += bf2f(h[2]); A[3] += bf2f(h[3]); }

__global__ __launch_bounds__(256) void gather_kernel(
        const unsigned short* __restrict__ Hs, const float* __restrict__ H0,
        const int* __restrict__ row_ptr, const int* __restrict__ col,
        const float* __restrict__ dinv, const float* __restrict__ alpha_p,
        unsigned short* __restrict__ Af, int n) {
    __shared__ __align__(16) unsigned short L[4][256];
    int wave = threadIdx.x >> 6;
    int lane = threadIdx.x & 63;
    int rbase = blockIdx.x * 4;
    int row = rbase + wave;
    float alpha = alpha_p[0];
    const u16x4* Hs4 = (const u16x4*)Hs;

    if (row < n) {
        int beg = row_ptr[row], end = row_ptr[row + 1];
        f32x4 a0 = 0.0f, a1 = 0.0f, a2 = 0.0f, a3 = 0.0f;
        int e = beg;
        for (; e + 8 <= end; e += 8) {             // 8 gathers in flight
            int j0 = col[e+0], j1 = col[e+1], j2 = col[e+2], j3 = col[e+3];
            int j4 = col[e+4], j5 = col[e+5], j6 = col[e+6], j7 = col[e+7];
            u16x4 h0 = Hs4[j0*64+lane], h1 = Hs4[j1*64+lane];
            u16x4 h2 = Hs4[j2*64+lane], h3 = Hs4[j3*64+lane];
            u16x4 h4 = Hs4[j4*64+lane], h5 = Hs4[j5*64+lane];
            u16x4 h6 = Hs4[j6*64+lane], h7 = Hs4[j7*64+lane];
            ACC(a0, h0) ACC(a1, h1) ACC(a2, h2) ACC(a3, h3)
            ACC(a0, h4) ACC(a1, h5) ACC(a2, h6) ACC(a3, h7)
        }
        for (; e + 4 <= end; e += 4) {
            int j0 = col[e+0], j1 = col[e+1], j2 = col[e+2], j3 = col[e+3];
            u16x4 h0 = Hs4[j0*64+lane], h1 = Hs4[j1*64+lane];
            u16x4 h2 = Hs4[j2*64+lane], h3 = Hs4[j3*64+lane];
            ACC(a0, h0) ACC(a1, h1) ACC(a2, h2) ACC(a3, h3)
        }
        for (; e < end; ++e) {
            int j = col[e];
            u16x4 h = Hs4[j*64+lane];
            ACC(a0, h)
        }
        // self loop: H/deg = Hs * dinv  =>  PH = dinv[row] * (sum + Hs_row)
        u16x4 hr = Hs4[row*64+lane];
        ACC(a2, hr)
        f32x4 acc = (a0 + a1) + (a2 + a3);
        float di = dinv[row];
        f32x4 h0v = __builtin_nontemporal_load((const f32x4*)H0 + row * 64 + lane);
        f32x4 init = (1.0f - alpha) * (di * acc) + alpha * h0v;
        u16x4 o;
        o[0] = f2bf(init[0]); o[1] = f2bf(init[1]);
        o[2] = f2bf(init[2]); o[3] = f2bf(init[3]);
        *(u16x4*)&L[wave][lane * 4] = o;
    }
    __syncthreads();

    // cooperative fragment-major store: t -> (kk, hi, r2, half)
    int t = threadIdx.x;
    int kk = t >> 5, hi = (t >> 3) & 3, r2 = (t >> 1) & 3, half = t & 1;
    int grow = rbase + r2;
    if (grow < n) {
        int k = kk * 32 + hi * 8 + half * 4;
        u16x4 o = *(const u16x4*)&L[r2][k];
        size_t fb = (size_t)(grow >> 4);
        size_t idx = (((fb * 8 + kk) * 64) + hi * 16 + (grow & 15)) * 8 + half * 4;
        *(u16x4*)(Af + idx) = o;
    }
}

// ---- GEMM: out = Af @ Wt' (identity pre-folded), zero LDS / zero barrier --
// 64-row blocks (grid 782); wave w owns cols [64w,64w+64). Per kk: 4 A-frag
// + 4 B-frag contiguous 1KB wave reads, 16 MFMA. Pure streaming.

__global__ __launch_bounds__(256) void gemm_kernel(
        const unsigned short* __restrict__ Af, const unsigned short* __restrict__ Wtp,
        float* __restrict__ out, int M) {
    int tid = threadIdx.x;
    int w = tid >> 6;
    int lane = tid & 63;
    int lo = lane & 15, hi = lane >> 4;
    int mr = blockIdx.x * 64;
    int nc = w * 64;
    int fb0 = mr >> 4;

    f32x4 acc[4][4] = {};
    for (int kk = 0; kk < 8; ++kk) {
        short8 a[4], b[4];
#pragma unroll
        for (int am = 0; am < 4; ++am)
            a[am] = *(const short8*)(Af + (((size_t)(fb0 + am) * 8 + kk) * 64 + lane) * 8);
#pragma unroll
        for (int bn = 0; bn < 4; ++bn)
            b[bn] = *(const short8*)(Wtp + (((size_t)(w * 4 + bn) * 8 + kk) * 64 + lane) * 8);
#pragma unroll
        for (int am = 0; am < 4; ++am)
#pragma unroll
            for (int bn = 0; bn < 4; ++bn)
                acc[am][bn] = __builtin_amdgcn_mfma_f32_16x16x32_bf16(
                    a[am], b[bn], acc[am][bn], 0, 0, 0);
    }

    // C/D layout: col = lane&15, row = (lane>>4)*4 + reg   [m89-verified]
#pragma unroll
    for (int am = 0; am < 4; ++am) {
        int rbase = mr + am * 16 + hi * 4;
#pragma unroll
        for (int r = 0; r < 4; ++r) {
            int row = rbase + r;
            if (row >= M) continue;
#pragma unroll
            for (int bn = 0; bn < 4; ++bn) {
                int c2 = nc + bn * 16 + lo;
                out[(size_t)row * F_DIM + c2] = acc[am][bn][r];
            }
        }
    }
}

// ---- launch ---------------------------------------------------------------

extern "C" void kernel_launch(void* const* d_in, const int* in_sizes, int n_in,
                              void* d_out, int out_size, void* d_ws, size_t ws_size,
                              hipStream_t stream) {
    const float* H     = (const float*)d_in[0];
    const int*   ei    = (const int*)d_in[1];
    const float* H0    = (const float*)d_in[2];
    const float* W     = (const float*)d_in[3];
    const float* lamda = (const float*)d_in[4];
    const float* alpha = (const float*)d_in[5];
    const int*   lp    = (const int*)d_in[6];

    int n = in_sizes[0] / F_DIM;
    int E = in_sizes[1] / 2;
    const int* src = ei;
    const int* dst = ei + E;
    float* out = (float*)d_out;

    int wpc4 = (n + 3) / 4;                // u8x4 words covering all nodes (12500)
    int nchunk = (E + CHUNK - 1) / CHUNK;  // 80
    int nb = (n + 256) / 256;              // scan blocks covering 0..n (196)

    char* ws = (char*)d_ws;
    size_t off = 0;
    auto alloc = [&](size_t bytes) -> void* {
        void* p = ws + off;
        off += (bytes + 255) & ~(size_t)255;
        return p;
    };
    unsigned* histS = (unsigned*)alloc((size_t)nchunk * wpc4 * 4);  // 4 MB
    unsigned* histD = (unsigned*)alloc((size_t)nchunk * wpc4 * 4);  // 4 MB
    unsigned* baseL = (unsigned*)alloc((size_t)nchunk * wpc4 * 4);  // 4 MB (u8)
    unsigned char* lrank = (unsigned char*)alloc((size_t)E);        // 0.8 MB
    int* cnt     = (int*)alloc((size_t)n * 4);
    int* row_ptr = (int*)alloc(((size_t)n + 1) * 4);
    int* blksum  = (int*)alloc((size_t)(nb + 8) * 4);
    float* dinv  = (float*)alloc((size_t)n * 4);
    int* colb    = (int*)alloc((size_t)E * 4);
    unsigned short* Wtp = (unsigned short*)alloc((size_t)F_DIM * F_DIM * 2);
    unsigned short* Hs  = (unsigned short*)alloc((size_t)n * F_DIM * 2);
    unsigned short* Af  = (unsigned short*)alloc(((size_t)n + 64) * F_DIM * 2);

    hist_kernel<<<nchunk * 2, 1024, 0, stream>>>(src, dst, histS, histD, lrank,
                                                 E, wpc4);
    int wgrid = (wpc4 + 255) / 256;        // 49 blocks -> 196 blksum entries
    sumbase_kernel<<<wgrid, 256, 0, stream>>>(histS, histD, cnt, dinv, baseL,
                                              blksum, wpc4, nchunk, n);
    rowptr_kernel<<<nb, 256, 0, stream>>>(cnt, blksum, row_ptr, n, nb);
    int nfill = (E + 255) / 256;
    int total4 = n * 64;
    int nhswt = (total4 + F_DIM * F_DIM + 255) / 256;
    fillhswt_kernel<<<nfill + nhswt, 256, 0, stream>>>(
        src, dst, row_ptr, (const unsigned char*)baseL, lrank, colb,
        H, dinv, Hs, W, Wtp, lamda, lp, E, wpc4, nfill, total4);
    gather_kernel<<<(n + 3) / 4, 256, 0, stream>>>(Hs, H0, row_ptr, colb, dinv,
                                                   alpha, Af, n);
    int mtiles = (n + 63) / 64;
    gemm_kernel<<<mtiles, 256, 0, stream>>>(Af, Wtp, out, n);
}

// Round 24
// 147.983 us; speedup vs baseline: 1.0681x; 1.0681x over previous
//
#include <hip/hip_runtime.h>
#include <math.h>

// GCNII graph convolution, N=50000, F=256, E=800000, f32 in/out.
// R24: R22 + ONLY the measured R23 win: gather Af-stores coalesced via
//      4-row LDS staging (WRITE 37.7->25MB, gather 72->68.8us). R23's
//      CHUNK=10000 reverted (doubled hist table writes + sumbase reads:
//      +10us). CHUNK=20000, u8 tables, fragment-major A+B, zero-LDS gemm.

#define F_DIM 256
#define CHUNK 20000

typedef __attribute__((ext_vector_type(4))) float f32x4;
typedef __attribute__((ext_vector_type(8))) short short8;
typedef __attribute__((ext_vector_type(4))) unsigned short u16x4;

static __device__ __forceinline__ unsigned short f2bf(float f) {
    unsigned int u = __float_as_uint(f);
    u += 0x7fffu + ((u >> 16) & 1u);
    return (unsigned short)(u >> 16);
}
static __device__ __forceinline__ float bf2f(unsigned short u) {
    return __uint_as_float((unsigned int)u << 16);
}

// ---- histogram: block = (chunk c, which). u8x4-packed LDS, all nodes ------

__global__ __launch_bounds__(1024) void hist_kernel(
        const int* __restrict__ src, const int* __restrict__ dst,
        unsigned* __restrict__ histS, unsigned* __restrict__ histD,
        unsigned char* __restrict__ lrank, int E, int wpc4) {
    __shared__ unsigned hist[12544];
    int b = blockIdx.x;
    int which = b & 1, c = b >> 1;
    int tid = threadIdx.x;
    int e0 = c * CHUNK;
    int e1 = e0 + CHUNK < E ? e0 + CHUNK : E;
    const int* eptr = which ? dst : src;
    unsigned* outh = which ? histD : histS;

    for (int w = tid; w < wpc4; w += 1024) hist[w] = 0;
    __syncthreads();
    for (int e = e0 + tid; e < e1; e += 1024) {
        int s = eptr[e];
        int sh = (s & 3) * 8;
        unsigned old = atomicAdd(&hist[s >> 2], 1u << sh);
        if (!which) lrank[e] = (unsigned char)((old >> sh) & 0xffu);
    }
    __syncthreads();
    for (int w = tid; w < wpc4; w += 1024)
        outh[(size_t)c * wpc4 + w] = hist[w];
}

// ---- histS/histD pass: cnt, dinv, u8-packed per-chunk bases, blk sums -----

__global__ __launch_bounds__(256) void sumbase_kernel(
        const unsigned* __restrict__ histS, const unsigned* __restrict__ histD,
        int* __restrict__ cnt, float* __restrict__ dinv,
        unsigned* __restrict__ baseL, int* __restrict__ blksum,
        int wpc4, int nchunk, int n) {
    int tid = threadIdx.x;
    int w = blockIdx.x * 256 + tid;
    unsigned s0 = 0, s1 = 0, s2 = 0, s3 = 0;
    unsigned d0 = 0, d1 = 0, d2 = 0, d3 = 0;
    if (w < wpc4) {
        for (int c = 0; c < nchunk; ++c) {
            unsigned vs = histS[(size_t)c * wpc4 + w];
            unsigned vd = histD[(size_t)c * wpc4 + w];
            baseL[(size_t)c * wpc4 + w] = s0 | (s1 << 8) | (s2 << 16) | (s3 << 24);
            s0 += vs & 0xffu; s1 += (vs >> 8) & 0xffu;
            s2 += (vs >> 16) & 0xffu; s3 += vs >> 24;
            d0 += vd & 0xffu; d1 += (vd >> 8) & 0xffu;
            d2 += (vd >> 16) & 0xffu; d3 += vd >> 24;
        }
        int i0 = 4 * w;
        unsigned sv[4] = {s0, s1, s2, s3};
        unsigned dv[4] = {d0, d1, d2, d3};
        for (int k = 0; k < 4; ++k) {
            if (i0 + k < n) {
                cnt[i0 + k] = (int)sv[k];
                dinv[i0 + k] = rsqrtf((float)dv[k] + 1.0f);
            }
        }
    }
    int contrib = (w < wpc4) ? (int)(s0 + s1 + s2 + s3) : 0;
    int lane = tid & 63, wid = tid >> 6;
    int v = contrib;
    for (int off = 32; off > 0; off >>= 1) v += __shfl_down(v, off, 64);
    if (lane == 0) blksum[4 * blockIdx.x + wid] = v;
}

// ---- row_ptr: per-block self-scan of blksum + local scan ------------------

__global__ __launch_bounds__(256) void rowptr_kernel(const int* __restrict__ cnt,
                                                     const int* __restrict__ blksum,
                                                     int* __restrict__ row_ptr,
                                                     int n, int nb) {
    int tid = threadIdx.x;
    int lane = tid & 63, w = tid >> 6;
    int bv = (tid < nb) ? blksum[tid] : 0;
    int bs = bv;
    for (int off = 1; off < 64; off <<= 1) {
        int t = __shfl_up(bv, off, 64);
        if (lane >= off) bv += t;
    }
    __shared__ int wsb[4];
    __shared__ int sbo[256];
    if (lane == 63) wsb[w] = bv;
    __syncthreads();
    if (tid == 0) {
        int run = 0;
        for (int k = 0; k < 4; ++k) { int t = wsb[k]; wsb[k] = run; run += t; }
    }
    __syncthreads();
    sbo[tid] = wsb[w] + bv - bs;
    __syncthreads();
    int blockoff = sbo[blockIdx.x];
    int i = blockIdx.x * 256 + tid;
    int s = (i < n) ? cnt[i] : 0;
    int v = s;
    for (int off = 1; off < 64; off <<= 1) {
        int t = __shfl_up(v, off, 64);
        if (lane >= off) v += t;
    }
    __shared__ int ws[4];
    if (lane == 63) ws[w] = v;
    __syncthreads();
    if (tid == 0) {
        int run = 0;
        for (int k = 0; k < 4; ++k) { int t = ws[k]; ws[k] = run; run += t; }
    }
    __syncthreads();
    if (i <= n) row_ptr[i] = blockoff + ws[w] + v - s;
}

// ---- merged: fill + Hs build + Wtp build (fragment-major) -----------------

__global__ __launch_bounds__(256) void fillhswt_kernel(
        const int* __restrict__ src, const int* __restrict__ dst,
        const int* __restrict__ row_ptr, const unsigned char* __restrict__ baseL8,
        const unsigned char* __restrict__ lrank, int* __restrict__ col,
        const float* __restrict__ H, const float* __restrict__ dinv,
        unsigned short* __restrict__ Hs,
        const float* __restrict__ W, unsigned short* __restrict__ Wtp,
        const float* __restrict__ lamda_p, const int* __restrict__ l_p,
        int E, int wpc4, int nfill, int total4) {
    int bid = blockIdx.x;
    int tid = threadIdx.x;
    if (bid < nfill) {
        int e = bid * 256 + tid;
        if (e < E) {
            int c = e / CHUNK;
            int s = src[e];
            unsigned lb = baseL8[(size_t)c * (4 * wpc4) + s];   // 2MB, L2-resident
            unsigned pos = (unsigned)row_ptr[s] + lb + lrank[e];
            col[pos] = dst[e];
        }
    } else {
        int i = (bid - nfill) * 256 + tid;   // f32x4 / u16x4 units
        if (i < total4) {
            int row = i >> 6;                 // 64 x f32x4 per row
            float d = dinv[row];
            f32x4 x = ((const f32x4*)H)[i];
            u16x4 o;
            o[0] = f2bf(x[0] * d); o[1] = f2bf(x[1] * d);
            o[2] = f2bf(x[2] * d); o[3] = f2bf(x[3] * d);
            ((u16x4*)Hs)[i] = o;
        } else {
            int t = i - total4;               // 0..65535 -> Wtp build
            if (t < F_DIM * F_DIM) {
                float beta = logf(lamda_p[0] / (float)l_p[0] + 1.0f);
                int nn = t >> 8, kf = t & 255;          // col, k
                float v = beta * W[kf * F_DIM + nn];
                if (kf == nn) v += 1.0f - beta;
                int cb = nn >> 4, lo = nn & 15;
                int kk = kf >> 5, ks = kf & 31;
                int hi = ks >> 3, el = ks & 7;
                int lane = hi * 16 + lo;
                Wtp[(((size_t)cb * 8 + kk) * 64 + lane) * 8 + el] = f2bf(v);
            }
        }
    }
}

// ---- gather: wave per row, 8-deep unroll; 4-row LDS stage -> coalesced
// fragment-major Af stores (128B-contiguous chunks).

#define ACC(A, h) { A[0] += bf2f(h[0]); A[1] += bf2f(h[1]); \
                    A[2] += bf2f(h[2]); A[3] += bf2f(h[3]); }

__global__ __launch_bounds__(256) void gather_kernel(
        const unsigned short* __restrict__ Hs, const float* __restrict__ H0,
        const int* __restrict__ row_ptr, const int* __restrict__ col,
        const float* __restrict__ dinv, const float* __restrict__ alpha_p,
        unsigned short* __restrict__ Af, int n) {
    __shared__ __align__(16) unsigned short L[4][256];
    int wave = threadIdx.x >> 6;
    int lane = threadIdx.x & 63;
    int rbase = blockIdx.x * 4;
    int row = rbase + wave;
    float alpha = alpha_p[0];
    const u16x4* Hs4 = (const u16x4*)Hs;

    if (row < n) {
        int beg = row_ptr[row], end = row_ptr[row + 1];
        f32x4 a0 = 0.0f, a1 = 0.0f, a2 = 0.0f, a3 = 0.0f;
        int e = beg;
        for (; e + 8 <= end; e += 8) {             // 8 gathers in flight
            int j0 = col[e+0], j1 = col[e+1], j2 = col[e+2], j3 = col[e+3];
            int j4 = col[e+4], j5 = col[e+5], j6 = col[e+6], j7 = col[e+7];
            u16x4 h0 = Hs4[j0*64+lane], h1 = Hs4[j1*64+lane];
            u16x4 h2 = Hs4[j2*64+lane], h3 = Hs4[j3*64+lane];
            u16x4 h4 = Hs4[j4*64+lane], h5 = Hs4[j5*64+lane];
            u16x4 h6 = Hs4[j6*64+lane], h7 = Hs4[j7*64+lane];
            ACC(a0, h0) ACC(a1, h1) ACC(a2, h2) ACC(a3, h3)
            ACC(a0, h4) ACC(a1, h5) ACC(a2, h6) ACC(a3, h7)
        }
        for (; e + 4 <= end; e += 4) {
            int j0 = col[e+0], j1 = col[e+1], j2 = col[e+2], j3 = col[e+3];
            u16x4 h0 = Hs4[j0*64+lane], h1 = Hs4[j1*64+lane];
            u16x4 h2 = Hs4[j2*64+lane], h3 = Hs4[j3*64+lane];
            ACC(a0, h0) ACC(a1, h1) ACC(a2, h2) ACC(a3, h3)
        }
        for (; e < end; ++e) {
            int j = col[e];
            u16x4 h = Hs4[j*64+lane];
            ACC(a0, h)
        }
        // self loop: H/deg = Hs * dinv  =>  PH = dinv[row] * (sum + Hs_row)
        u16x4 hr = Hs4[row*64+lane];
        ACC(a2, hr)
        f32x4 acc = (a0 + a1) + (a2 + a3);
        float di = dinv[row];
        f32x4 h0v = __builtin_nontemporal_load((const f32x4*)H0 + row * 64 + lane);
        f32x4 init = (1.0f - alpha) * (di * acc) + alpha * h0v;
        u16x4 o;
        o[0] = f2bf(init[0]); o[1] = f2bf(init[1]);
        o[2] = f2bf(init[2]); o[3] = f2bf(init[3]);
        *(u16x4*)&L[wave][lane * 4] = o;
    }
    __syncthreads();

    // cooperative fragment-major store: t -> (kk, hi, r2, half)
    int t = threadIdx.x;
    int kk = t >> 5, hi = (t >> 3) & 3, r2 = (t >> 1) & 3, half = t & 1;
    int grow = rbase + r2;
    if (grow < n) {
        int k = kk * 32 + hi * 8 + half * 4;
        u16x4 o = *(const u16x4*)&L[r2][k];
        size_t fb = (size_t)(grow >> 4);
        size_t idx = (((fb * 8 + kk) * 64) + hi * 16 + (grow & 15)) * 8 + half * 4;
        *(u16x4*)(Af + idx) = o;
    }
}

// ---- GEMM: out = Af @ Wt' (identity pre-folded), zero LDS / zero barrier --
// 64-row blocks (grid 782); wave w owns cols [64w,64w+64). Per kk: 4 A-frag
// + 4 B-frag contiguous 1KB wave reads, 16 MFMA. Pure streaming.

__global__ __launch_bounds__(256) void gemm_kernel(
        const unsigned short* __restrict__ Af, const unsigned short* __restrict__ Wtp,
        float* __restrict__ out, int M) {
    int tid = threadIdx.x;
    int w = tid >> 6;
    int lane = tid & 63;
    int lo = lane & 15, hi = lane >> 4;
    int mr = blockIdx.x * 64;
    int nc = w * 64;
    int fb0 = mr >> 4;

    f32x4 acc[4][4] = {};
    for (int kk = 0; kk < 8; ++kk) {
        short8 a[4], b[4];
#pragma unroll
        for (int am = 0; am < 4; ++am)
            a[am] = *(const short8*)(Af + (((size_t)(fb0 + am) * 8 + kk) * 64 + lane) * 8);
#pragma unroll
        for (int bn = 0; bn < 4; ++bn)
            b[bn] = *(const short8*)(Wtp + (((size_t)(w * 4 + bn) * 8 + kk) * 64 + lane) * 8);
#pragma unroll
        for (int am = 0; am < 4; ++am)
#pragma unroll
            for (int bn = 0; bn < 4; ++bn)
                acc[am][bn] = __builtin_amdgcn_mfma_f32_16x16x32_bf16(
                    a[am], b[bn], acc[am][bn], 0, 0, 0);
    }

    // C/D layout: col = lane&15, row = (lane>>4)*4 + reg   [m89-verified]
#pragma unroll
    for (int am = 0; am < 4; ++am) {
        int rbase = mr + am * 16 + hi * 4;
#pragma unroll
        for (int r = 0; r < 4; ++r) {
            int row = rbase + r;
            if (row >= M) continue;
#pragma unroll
            for (int bn = 0; bn < 4; ++bn) {
                int c2 = nc + bn * 16 + lo;
                out[(size_t)row * F_DIM + c2] = acc[am][bn][r];
            }
        }
    }
}

// ---- launch ---------------------------------------------------------------

extern "C" void kernel_launch(void* const* d_in, const int* in_sizes, int n_in,
                              void* d_out, int out_size, void* d_ws, size_t ws_size,
                              hipStream_t stream) {
    const float* H     = (const float*)d_in[0];
    const int*   ei    = (const int*)d_in[1];
    const float* H0    = (const float*)d_in[2];
    const float* W     = (const float*)d_in[3];
    const float* lamda = (const float*)d_in[4];
    const float* alpha = (const float*)d_in[5];
    const int*   lp    = (const int*)d_in[6];

    int n = in_sizes[0] / F_DIM;
    int E = in_sizes[1] / 2;
    const int* src = ei;
    const int* dst = ei + E;
    float* out = (float*)d_out;

    int wpc4 = (n + 3) / 4;                // u8x4 words covering all nodes (12500)
    int nchunk = (E + CHUNK - 1) / CHUNK;  // 40
    int nb = (n + 256) / 256;              // scan blocks covering 0..n (196)

    char* ws = (char*)d_ws;
    size_t off = 0;
    auto alloc = [&](size_t bytes) -> void* {
        void* p = ws + off;
        off += (bytes + 255) & ~(size_t)255;
        return p;
    };
    unsigned* histS = (unsigned*)alloc((size_t)nchunk * wpc4 * 4);  // 2 MB
    unsigned* histD = (unsigned*)alloc((size_t)nchunk * wpc4 * 4);  // 2 MB
    unsigned* baseL = (unsigned*)alloc((size_t)nchunk * wpc4 * 4);  // 2 MB (u8)
    unsigned char* lrank = (unsigned char*)alloc((size_t)E);        // 0.8 MB
    int* cnt     = (int*)alloc((size_t)n * 4);
    int* row_ptr = (int*)alloc(((size_t)n + 1) * 4);
    int* blksum  = (int*)alloc((size_t)(nb + 8) * 4);
    float* dinv  = (float*)alloc((size_t)n * 4);
    int* colb    = (int*)alloc((size_t)E * 4);
    unsigned short* Wtp = (unsigned short*)alloc((size_t)F_DIM * F_DIM * 2);
    unsigned short* Hs  = (unsigned short*)alloc((size_t)n * F_DIM * 2);
    unsigned short* Af  = (unsigned short*)alloc(((size_t)n + 64) * F_DIM * 2);

    hist_kernel<<<nchunk * 2, 1024, 0, stream>>>(src, dst, histS, histD, lrank,
                                                 E, wpc4);
    int wgrid = (wpc4 + 255) / 256;        // 49 blocks -> 196 blksum entries
    sumbase_kernel<<<wgrid, 256, 0, stream>>>(histS, histD, cnt, dinv, baseL,
                                              blksum, wpc4, nchunk, n);
    rowptr_kernel<<<nb, 256, 0, stream>>>(cnt, blksum, row_ptr, n, nb);
    int nfill = (E + 255) / 256;
    int total4 = n * 64;
    int nhswt = (total4 + F_DIM * F_DIM + 255) / 256;
    fillhswt_kernel<<<nfill + nhswt, 256, 0, stream>>>(
        src, dst, row_ptr, (const unsigned char*)baseL, lrank, colb,
        H, dinv, Hs, W, Wtp, lamda, lp, E, wpc4, nfill, total4);
    gather_kernel<<<(n + 3) / 4, 256, 0, stream>>>(Hs, H0, row_ptr, colb, dinv,
                                                   alpha, Af, n);
    int mtiles = (n + 63) / 64;
    gemm_kernel<<<mtiles, 256, 0, stream>>>(Af, Wtp, out, n);
}